// Round 6
// baseline (520.933 us; speedup 1.0000x reference)
//
#include <hip/hip_runtime.h>
#include <stdint.h>

#define HID    1024
#define EXPERTS 8
#define TOPK   2
#define INNER  2048
#define NTOK   8192            // B*S = 4*2048
#define NPAIR  (NTOK * TOPK)   // 16384
#define MAXT   136             // max expert-pure 128-row tiles: 16384/128 + 8

#define BM 128
#define BN 128
#define BK 64                  // 128B LDS rows -> swizzle spreads all 32 banks

typedef _Float16 f16;
typedef f16   f16x8 __attribute__((ext_vector_type(8)));
typedef float f32x4 __attribute__((ext_vector_type(4)));

// ---- async global->LDS (16B/lane, wave-uniform LDS base + lane*16) ----
__device__ __forceinline__ void gload_lds16(const void* g, void* l) {
  __builtin_amdgcn_global_load_lds(
      (const __attribute__((address_space(1))) void*)g,
      (__attribute__((address_space(3))) void*)l, 16, 0, 0);
}

// =====================  router: logits, top-2, softmax (NO atomics)  ========
__global__ void router_kernel(const float* __restrict__ x,
                              const float* __restrict__ Wr,
                              const float* __restrict__ br,
                              int* __restrict__ e_sel, float* __restrict__ w_sel) {
  int gid  = blockIdx.x * blockDim.x + threadIdx.x;
  int wid  = gid >> 6;           // one wave per token
  int lane = gid & 63;
  if (wid >= NTOK) return;

  const f32x4* xr = (const f32x4*)(x + (size_t)wid * HID);
  float acc[EXPERTS];
#pragma unroll
  for (int e = 0; e < EXPERTS; ++e) acc[e] = 0.f;

#pragma unroll
  for (int j = 0; j < HID / 256; ++j) {
    f32x4 xv = xr[j * 64 + lane];
    int   k  = (j * 64 + lane) * 4;
    const float* wr = Wr + (size_t)k * EXPERTS;
#pragma unroll
    for (int r = 0; r < 4; ++r) {
      float xs = xv[r];
      f32x4 w0 = *(const f32x4*)(wr + r * 8);
      f32x4 w1 = *(const f32x4*)(wr + r * 8 + 4);
#pragma unroll
      for (int e = 0; e < 4; ++e) { acc[e] += xs * w0[e]; acc[4 + e] += xs * w1[e]; }
    }
  }
#pragma unroll
  for (int e = 0; e < EXPERTS; ++e) {
#pragma unroll
    for (int off = 32; off > 0; off >>= 1) acc[e] += __shfl_xor(acc[e], off);
  }
  if (lane == 0) {
    float lg[EXPERTS];
#pragma unroll
    for (int e = 0; e < EXPERTS; ++e) lg[e] = acc[e] + br[e];
    int e0 = 0; float l0 = lg[0];
#pragma unroll
    for (int e = 1; e < EXPERTS; ++e) if (lg[e] > l0) { l0 = lg[e]; e0 = e; }
    int e1 = -1; float l1 = -3.4e38f;
#pragma unroll
    for (int e = 0; e < EXPERTS; ++e) if (e != e0 && lg[e] > l1) { l1 = lg[e]; e1 = e; }
    float a  = __expf(l1 - l0);          // l1 <= l0, a <= 1
    float w0 = 1.f / (1.f + a);
    float w1 = a * w0;
    e_sel[wid * 2]     = e0;  e_sel[wid * 2 + 1] = e1;
    w_sel[wid * 2]     = w0;  w_sel[wid * 2 + 1] = w1;
  }
}

// ====  dispatch: counts + scan + tile map + scatter, 1 block, NO atomics  ===
// 1024 threads; thread t owns pairs [t*16, t*16+16) (= tokens t*8..t*8+7).
__global__ __launch_bounds__(1024) void dispatch_kernel(
    const int* __restrict__ e_sel, const float* __restrict__ w_sel,
    int* __restrict__ tok_list, float* __restrict__ wt_list,
    int* __restrict__ counts, int* __restrict__ bases,
    int* __restrict__ tile_e, int* __restrict__ tile_m0,
    int* __restrict__ tinfo) {
  __shared__ int scnt[EXPERTS][1024];
  __shared__ int etot[EXPERTS];
  __shared__ int ebase[EXPERTS];
  int tid = threadIdx.x, lane = tid & 63, wv = tid >> 6;

  // phase 1: local histogram (static-indexed: 8 compares per pair)
  int myE[16]; float myW[16];
  int lc[EXPERTS];
#pragma unroll
  for (int e = 0; e < EXPERTS; ++e) lc[e] = 0;
#pragma unroll
  for (int i = 0; i < 16; ++i) {
    int p = tid * 16 + i;
    myE[i] = e_sel[p];
    myW[i] = w_sel[p];
#pragma unroll
    for (int e = 0; e < EXPERTS; ++e) lc[e] += (myE[i] == e);
  }
#pragma unroll
  for (int e = 0; e < EXPERTS; ++e) scnt[e][tid] = lc[e];
  __syncthreads();

  // phase 2: per-expert exclusive scan over 1024 threads (wave wv owns expert wv)
  if (wv < EXPERTS) {
    int run = 0;
    for (int c = 0; c < 16; ++c) {
      int v = scnt[wv][c * 64 + lane];
      int incl = v;
#pragma unroll
      for (int off = 1; off < 64; off <<= 1) {
        int n = __shfl_up(incl, off);
        if (lane >= off) incl += n;
      }
      scnt[wv][c * 64 + lane] = run + incl - v;
      run += __shfl(incl, 63);
    }
    if (lane == 0) etot[wv] = run;
  }
  __syncthreads();

  // phase 2b: bases + tile map (serial, tiny)
  if (tid == 0) {
    int s = 0, t = 0;
    for (int e = 0; e < EXPERTS; ++e) {
      ebase[e] = s; bases[e] = s; counts[e] = etot[e];
      for (int m0 = 0; m0 < etot[e]; m0 += BM) { tile_e[t] = e; tile_m0[t] = m0; ++t; }
      s += etot[e];
    }
    tinfo[0] = t;
  }
  __syncthreads();

  // phase 3: scatter at exact offsets (deterministic, token-sorted per expert)
  int cur[EXPERTS];
#pragma unroll
  for (int e = 0; e < EXPERTS; ++e) cur[e] = ebase[e] + scnt[e][tid];
#pragma unroll
  for (int i = 0; i < 16; ++i) {
    int p = 0;
#pragma unroll
    for (int e = 0; e < EXPERTS; ++e) if (myE[i] == e) p = cur[e]++;
    tok_list[p] = (tid * 16 + i) >> 1;
    wt_list[p]  = myW[i];
  }
}

// =====================  pre-pass: fp32 -> fp16 (+transpose for weights)  ====
__global__ void convert_x_kernel(const float* __restrict__ x,
                                 f16* __restrict__ x16, int n8) {
  int i = blockIdx.x * blockDim.x + threadIdx.x;
  int stride = gridDim.x * blockDim.x;
  for (; i < n8; i += stride) {
    f32x4 a = ((const f32x4*)x)[i * 2];
    f32x4 b = ((const f32x4*)x)[i * 2 + 1];
    f16x8 o;
#pragma unroll
    for (int j = 0; j < 4; ++j) { o[j] = (f16)a[j]; o[4 + j] = (f16)b[j]; }
    ((f16x8*)x16)[i] = o;
  }
}

// src [R][C] fp32 -> dst [C][R] fp16, one matrix per blockIdx.z
__global__ void transpose_cvt_kernel(const float* __restrict__ src,
                                     f16* __restrict__ dst, int R, int C) {
  __shared__ float tile[32][33];
  int z = blockIdx.z;
  src += (size_t)z * R * C;
  dst += (size_t)z * R * C;
  int c0 = blockIdx.x * 32, r0 = blockIdx.y * 32;
  int tx = threadIdx.x, ty = threadIdx.y;  // blockDim = (32, 8)
#pragma unroll
  for (int i = 0; i < 4; ++i)
    tile[ty + i * 8][tx] = src[(size_t)(r0 + ty + i * 8) * C + c0 + tx];
  __syncthreads();
#pragma unroll
  for (int i = 0; i < 4; ++i)
    dst[(size_t)(c0 + ty + i * 8) * R + r0 + tx] = (f16)tile[tx][ty + i * 8];
}

// ============================================================================
// GEMM core (both kernels): 128x128 tile, BK=64, 4 waves (2x2 of 64x64).
// LDS layout: per K-step, [128 rows][8 chunks of 16B]; stored chunk (row,c)
// holds global chunk (row, c^(row&7))  -> staged by pre-swizzling the GLOBAL
// source address (gload_lds dest stays linear, rule 21). Fragment reads XOR
// the same pattern -> uniform ~2-way bank spread (free).
// 2-phase pipeline: STAGE(next buf) issued before ds_read+MFMA of current;
// one __syncthreads per K-step (its implicit vmcnt(0)/lgkmcnt(0) drains both).
// ============================================================================

#define GEMM_STAGE(AS, BS) do {                                   \
  _Pragma("unroll") for (int i_ = 0; i_ < 4; ++i_) {              \
    gload_lds16(gA[i_], &(AS)[i_ * 2048 + wid * 512]);            \
    gload_lds16(gB[i_], &(BS)[i_ * 2048 + wid * 512]);            \
    gA[i_] += BK; gB[i_] += BK;                                   \
  }                                                               \
} while (0)

#define GEMM_COMPUTE(AS, BS) do {                                               \
  _Pragma("unroll") for (int kk_ = 0; kk_ < 2; ++kk_) {                         \
    int cko_ = kk_ ? colk1 : colk0;                                             \
    f16x8 af_[4], bf_[4];                                                       \
    _Pragma("unroll") for (int mi_ = 0; mi_ < 4; ++mi_)                         \
      af_[mi_] = *(const f16x8*)&(AS)[(wm + mi_ * 16 + ar) * 64 + cko_];        \
    _Pragma("unroll") for (int ni_ = 0; ni_ < 4; ++ni_)                         \
      bf_[ni_] = *(const f16x8*)&(BS)[(wn + ni_ * 16 + ar) * 64 + cko_];        \
    _Pragma("unroll") for (int mi_ = 0; mi_ < 4; ++mi_)                         \
      _Pragma("unroll") for (int ni_ = 0; ni_ < 4; ++ni_)                       \
        acc[mi_][ni_] = __builtin_amdgcn_mfma_f32_16x16x32_f16(                 \
            af_[mi_], bf_[ni_], acc[mi_][ni_], 0, 0, 0);                        \
  }                                                                             \
} while (0)

// =====================  GEMM1: h = relu(x @ W1 + b1)  =======================
__global__ __launch_bounds__(256) void gemm1_kernel(
    const f16* __restrict__ x16, const f16* __restrict__ w1t,
    const float* __restrict__ b1, const int* __restrict__ tok_list,
    const int* __restrict__ counts, const int* __restrict__ bases,
    const int* __restrict__ tile_e, const int* __restrict__ tile_m0,
    const int* __restrict__ tinfo, int c0,
    f16* __restrict__ h16) {
  int g = blockIdx.y;
  int t = c0 + g;
  if (t >= tinfo[0]) return;
  int e    = tile_e[t];
  int m0   = tile_m0[t];
  int cnt  = counts[e];
  int base = bases[e];
  int n0   = blockIdx.x * BN;
  const f16* Bg = w1t + (size_t)e * INNER * HID;

  __shared__ f16 As0[BM * BK], As1[BM * BK];
  __shared__ f16 Bs0[BM * BK], Bs1[BM * BK];

  int tid = threadIdx.x;
  int lane = tid & 63, wid = tid >> 6;
  int wm = (wid >> 1) * 64, wn = (wid & 1) * 64;

  // staging: thread t, issue i -> chunk i*256+t -> (row = i*32 + t>>3, col = t&7)
  // source col pre-swizzled: gcol = (t&7) ^ (row&7), row&7 == (t>>3)&7
  int trow = tid >> 3;
  int gcol = (tid & 7) ^ (trow & 7);
  const f16* gA[4];
  const f16* gB[4];
#pragma unroll
  for (int i = 0; i < 4; ++i) {
    int row = i * 32 + trow;
    int tok = tok_list[base + min(m0 + row, cnt - 1)];
    gA[i] = x16 + (size_t)tok * HID + gcol * 8;
    gB[i] = Bg + (size_t)(n0 + row) * HID + gcol * 8;
  }

  f32x4 acc[4][4];
#pragma unroll
  for (int i = 0; i < 4; ++i)
#pragma unroll
    for (int j = 0; j < 4; ++j) acc[i][j] = (f32x4){0.f, 0.f, 0.f, 0.f};

  int ar = lane & 15, hi = lane >> 4;
  int sa = ar & 7;
  int colk0 = ((hi) ^ sa) * 8;        // kk=0: logical chunk col = hi
  int colk1 = ((4 + hi) ^ sa) * 8;    // kk=1: logical chunk col = 4+hi

  GEMM_STAGE(As0, Bs0);
  __syncthreads();
  for (int ks = 0; ks < HID / BK; ks += 2) {
    GEMM_STAGE(As1, Bs1);               // stage step ks+1
    GEMM_COMPUTE(As0, Bs0);             // compute step ks
    __syncthreads();
    if (ks + 2 < HID / BK) GEMM_STAGE(As0, Bs0);  // stage step ks+2
    GEMM_COMPUTE(As1, Bs1);             // compute step ks+1
    __syncthreads();
  }

  // epilogue: + b1, relu, store fp16 to chunk-local h.  C/D: col=lane&15, row=(lane>>4)*4+r
  int col = lane & 15, rb = hi * 4;
  float bb[4];
#pragma unroll
  for (int ni = 0; ni < 4; ++ni) bb[ni] = b1[e * INNER + n0 + wn + ni * 16 + col];
#pragma unroll
  for (int mi = 0; mi < 4; ++mi)
#pragma unroll
    for (int r = 0; r < 4; ++r) {
      int ml = wm + mi * 16 + rb + r;        // row within tile
      if (m0 + ml < cnt) {
        size_t rowoff = (size_t)(g * BM + ml) * INNER + n0 + wn + col;
#pragma unroll
        for (int ni = 0; ni < 4; ++ni) {
          float v = acc[mi][ni][r] + bb[ni];
          h16[rowoff + ni * 16] = (f16)fmaxf(v, 0.f);
        }
      }
    }
}

// =====================  GEMM2: out += w * (h @ W2 + b2)  ====================
__global__ __launch_bounds__(256) void gemm2_kernel(
    const f16* __restrict__ h16, const f16* __restrict__ w2t,
    const float* __restrict__ b2, const int* __restrict__ tok_list,
    const float* __restrict__ wt_list, const int* __restrict__ counts,
    const int* __restrict__ bases,
    const int* __restrict__ tile_e, const int* __restrict__ tile_m0,
    const int* __restrict__ tinfo, int c0,
    float* __restrict__ out) {
  int g = blockIdx.y;
  int t = c0 + g;
  if (t >= tinfo[0]) return;
  int e    = tile_e[t];
  int m0   = tile_m0[t];
  int cnt  = counts[e];
  int base = bases[e];
  int d0   = blockIdx.x * BN;
  const f16* Bg = w2t + (size_t)e * HID * INNER;  // [d][n]

  __shared__ f16 As0[BM * BK], As1[BM * BK];
  __shared__ f16 Bs0[BM * BK], Bs1[BM * BK];

  int tid = threadIdx.x;
  int lane = tid & 63, wid = tid >> 6;
  int wm = (wid >> 1) * 64, wn = (wid & 1) * 64;

  int trow = tid >> 3;
  int gcol = (tid & 7) ^ (trow & 7);
  const f16* gA[4];
  const f16* gB[4];
#pragma unroll
  for (int i = 0; i < 4; ++i) {
    int row  = i * 32 + trow;
    int lrow = min(m0 + row, cnt - 1) - m0;     // chunk-local h row
    gA[i] = h16 + (size_t)(g * BM + lrow) * INNER + gcol * 8;
    gB[i] = Bg + (size_t)(d0 + row) * INNER + gcol * 8;
  }

  f32x4 acc[4][4];
#pragma unroll
  for (int i = 0; i < 4; ++i)
#pragma unroll
    for (int j = 0; j < 4; ++j) acc[i][j] = (f32x4){0.f, 0.f, 0.f, 0.f};

  int ar = lane & 15, hi = lane >> 4;
  int sa = ar & 7;
  int colk0 = ((hi) ^ sa) * 8;
  int colk1 = ((4 + hi) ^ sa) * 8;

  GEMM_STAGE(As0, Bs0);
  __syncthreads();
  for (int ks = 0; ks < INNER / BK; ks += 2) {
    GEMM_STAGE(As1, Bs1);
    GEMM_COMPUTE(As0, Bs0);
    __syncthreads();
    if (ks + 2 < INNER / BK) GEMM_STAGE(As0, Bs0);
    GEMM_COMPUTE(As1, Bs1);
    __syncthreads();
  }

  int col = lane & 15, rb = hi * 4;
  float bb[4];
#pragma unroll
  for (int ni = 0; ni < 4; ++ni) bb[ni] = b2[e * HID + d0 + wn + ni * 16 + col];
#pragma unroll
  for (int mi = 0; mi < 4; ++mi)
#pragma unroll
    for (int r = 0; r < 4; ++r) {
      int ml = wm + mi * 16 + rb + r;
      if (m0 + ml < cnt) {
        int   p   = base + m0 + ml;
        int   tok = tok_list[p];
        float w   = wt_list[p];
        float* orow = out + (size_t)tok * HID + d0 + wn + col;
#pragma unroll
        for (int ni = 0; ni < 4; ++ni) {
          float v = acc[mi][ni][r] + bb[ni];
          atomicAdd(orow + ni * 16, v * w);
        }
      }
    }
}

// ===========================================================================
extern "C" void kernel_launch(void* const* d_in, const int* in_sizes, int n_in,
                              void* d_out, int out_size, void* d_ws, size_t ws_size,
                              hipStream_t stream) {
  (void)in_sizes; (void)n_in;
  const float* x  = (const float*)d_in[0];
  const float* Wr = (const float*)d_in[1];
  const float* br = (const float*)d_in[2];
  const float* W1 = (const float*)d_in[3];
  const float* b1 = (const float*)d_in[4];
  const float* W2 = (const float*)d_in[5];
  const float* b2 = (const float*)d_in[6];
  float* out = (float*)d_out;

  char*  ws  = (char*)d_ws;
  size_t off = 0;
  auto alloc = [&](size_t bytes) {
    char* p = ws + off;
    off += bytes; off = (off + 255) & ~(size_t)255;
    return p;
  };
  // small buffers first (fixed ~0.6 MB)
  int*   tok_list = (int*)alloc(NPAIR * sizeof(int));
  float* wt_list  = (float*)alloc(NPAIR * sizeof(float));
  int*   e_sel    = (int*)alloc(NTOK * 2 * sizeof(int));
  float* w_sel    = (float*)alloc(NTOK * 2 * sizeof(float));
  int*   counts   = (int*)alloc(EXPERTS * sizeof(int));
  int*   bases    = (int*)alloc(EXPERTS * sizeof(int));
  int*   tile_e   = (int*)alloc(MAXT * sizeof(int));
  int*   tile_m0  = (int*)alloc(MAXT * sizeof(int));
  int*   tinfo    = (int*)alloc(16 * sizeof(int));
  // large fixed buffers (~84 MB total with the above)
  f16*   w1t      = (f16*)alloc((size_t)EXPERTS * HID * INNER * sizeof(f16));
  f16*   w2t      = (f16*)alloc((size_t)EXPERTS * HID * INNER * sizeof(f16));
  f16*   x16      = (f16*)alloc((size_t)NTOK * HID * sizeof(f16));
  // h chunk buffer: whatever fits in the remaining workspace
  const size_t TILE_BYTES = (size_t)BM * INNER * sizeof(f16);  // 512 KB
  size_t rem = (ws_size > off) ? (ws_size - off) : 0;
  int G = (int)(rem / TILE_BYTES);
  if (G < 1) G = 1;            // last resort (would overflow; needs ws >= ~85MB)
  if (G > MAXT) G = MAXT;
  int nch = (MAXT + G - 1) / G;
  f16* h16 = (f16*)(ws + off);

  hipMemsetAsync(out, 0, (size_t)out_size * sizeof(float), stream);

  convert_x_kernel<<<2048, 256, 0, stream>>>(x, x16, NTOK * HID / 8);
  transpose_cvt_kernel<<<dim3(INNER / 32, HID / 32, EXPERTS), dim3(32, 8), 0, stream>>>(
      W1, w1t, HID, INNER);
  transpose_cvt_kernel<<<dim3(HID / 32, INNER / 32, EXPERTS), dim3(32, 8), 0, stream>>>(
      W2, w2t, INNER, HID);
  router_kernel<<<NTOK / 4, 256, 0, stream>>>(x, Wr, br, e_sel, w_sel);
  dispatch_kernel<<<1, 1024, 0, stream>>>(e_sel, w_sel, tok_list, wt_list,
                                          counts, bases, tile_e, tile_m0, tinfo);

  for (int c = 0; c < nch; ++c) {
    int c0 = c * G;
    int gy = (MAXT - c0 < G) ? (MAXT - c0) : G;
    gemm1_kernel<<<dim3(INNER / BN, gy, 1), 256, 0, stream>>>(
        x16, w1t, b1, tok_list, counts, bases, tile_e, tile_m0, tinfo, c0, h16);
    gemm2_kernel<<<dim3(HID / BN, gy, 1), 256, 0, stream>>>(
        h16, w2t, b2, tok_list, wt_list, counts, bases, tile_e, tile_m0, tinfo, c0, out);
  }
}